// Round 7
// baseline (146.501 us; speedup 1.0000x reference)
//
#include <hip/hip_runtime.h>
#include <stdint.h>

// EATransformerMHS: B=2,H=12,S=256,E=64,L=25,K=768
// out[b,j,l,i] = sum_k p[b,k/64,i,j]*(v[b,k/64,j,k%64] + rel[b,i,j,k])*W[l,k] + b[l]
//
// Round-7: MFMA col = j (was i). rel[b][i][j][k] has 3KB stride between
// consecutive j -> one wave instruction's 16 rows now span 45KB (was 12MB),
// fixing DRAM channel/page locality. p loads become lane-contiguous (pt
// kernel deleted). Out stores are 4B-scattered; i-octet XCD swizzle groups
// the 8 blocks sharing each out cache line onto one XCD for L2 write merge.
// Compute structure identical to round 6: 2-buffer {rel,A,pv} software
// pipeline, pv folded into MFMA B, value term via wv epilogue.

#define Bb 2
#define Hh 12
#define Ss 256
#define Ee 64
#define Ll 25
#define Kk 768

typedef __attribute__((ext_vector_type(8))) short bf16x8;
typedef __attribute__((ext_vector_type(4))) float f32x4;

#define NFRAG (Hh * 4)
#define AB_BYTES ((size_t)NFRAG * 64 * 8 * 2)    // 49152
#define WV_BYTES ((size_t)Bb * Ss * Hh * 32 * 4) // 786432

__device__ __forceinline__ ushort f2bf(float x) {  // RNE f32->bf16
    union { float f; uint32_t u; } u; u.f = x;
    uint32_t r = u.u + 0x7fff + ((u.u >> 16) & 1);
    return (ushort)(r >> 16);
}

// Pack W[L,K] into per-lane A-fragments: frag fi=h*4+ks*2+Lt,
// lane holds A[l=Lt*16+(lane&15), k=h*64+ks*32+(lane>>4)*8+t].
__global__ void a_pack_kernel(const float* __restrict__ W, ushort* __restrict__ ab) {
    int idx = blockIdx.x * 256 + threadIdx.x;
    if (idx >= NFRAG * 64) return;
    int lane = idx & 63, fi = idx >> 6;
    int Lt = fi & 1, ks = (fi >> 1) & 1, h = fi >> 2;
    int l = Lt * 16 + (lane & 15);
    int k0 = h * Ee + ks * 32 + (lane >> 4) * 8;
    ushort* dst = ab + (size_t)idx * 8;
#pragma unroll
    for (int t = 0; t < 8; ++t)
        dst[t] = (l < Ll) ? f2bf(W[l * Kk + k0 + t]) : (ushort)0;
}

// wv[b][j][h][l(pad32)] = sum_e W[l, h*64+e] * v[b,h,j,e]   (f32 exact)
__global__ void wv_kernel(const float* __restrict__ W, const float* __restrict__ v,
                          float* __restrict__ wv) {
    const int bj = blockIdx.x;
    const int b = bj >> 8, j = bj & (Ss - 1);
    const int t = threadIdx.x;            // 384 = 12h x 32l
    const int h = t >> 5, l = t & 31;
    float acc = 0.f;
    if (l < Ll) {
        const float* wrow = W + l * Kk + h * Ee;
        const float* vrow = v + ((size_t)(b * Hh + h) * Ss + j) * Ee;
#pragma unroll
        for (int e = 0; e < Ee; ++e) acc = __builtin_fmaf(wrow[e], vrow[e], acc);
    }
    wv[((size_t)bj * Hh + h) * 32 + l] = acc;
}

struct Buf {
    float4 r0, r1, r2, r3;        // rel (16 VGPR)
    bf16x8 A00, A01, A10, A11;    // A-frags (16 VGPR)
    float pv;                     // p (1 VGPR)
};

__global__ __launch_bounds__(256, 4) void mhs_jcol(
    const float* __restrict__ p,    // [B,H,S,S]
    const float* __restrict__ rel,  // [B,S,S,K]
    const ushort* __restrict__ ab,  // packed A frags
    const float* __restrict__ wv,   // [B,S,H,32]
    const float* __restrict__ bias, // [L]
    float* __restrict__ out)        // [B,S,L,S]
{
    // physical->logical swizzle: XCD = bid%8 (round-robin assumption).
    // Group each i-octet's 32 blocks (8 i x 4 jb) onto one XCD so the 8
    // blocks sharing each 32B out-line (i0..i0+7) merge writes in that L2.
    const int bid = blockIdx.x;
    const int xcd = bid & 7, idx = bid >> 3;         // idx 0..255
    const int slot = idx >> 5, within = idx & 31;    // slot 0..7
    const int g = slot * 8 + xcd;                    // octet-group 0..63
    const int n = g * 32 + within;                   // logical block 0..2047
    const int jb = n & 3, i = (n >> 2) & (Ss - 1), b = n >> 10;

    const int tid = threadIdx.x;
    const int w = tid >> 6, lane = tid & 63;
    const int col = lane & 15, grp = lane >> 4;
    const int j = jb * 64 + w * 16 + col;            // this lane's MFMA column

    const float* relp = rel + ((size_t)(b * Ss + i) * Ss + j) * Kk + grp * 8;
    const ushort* abl = ab + lane * 8;
    const float* pb = p + ((size_t)(b * Hh) * Ss + i) * Ss + j;   // + h*Ss*Ss
    const float* wvb = wv + ((size_t)(b * Ss + j) * Hh) * 32 + grp * 4;

    f32x4 acc0 = {0.f, 0.f, 0.f, 0.f};
    f32x4 acc1 = {0.f, 0.f, 0.f, 0.f};

    auto load = [&](Buf& o, int h) {
        const float* rb = relp + h * Ee;
        o.r0 = *(const float4*)(rb);
        o.r1 = *(const float4*)(rb + 4);
        o.r2 = *(const float4*)(rb + 32);
        o.r3 = *(const float4*)(rb + 36);
        const ushort* ap = abl + (size_t)h * 2048;
        o.A00 = *(const bf16x8*)(ap);
        o.A01 = *(const bf16x8*)(ap + 512);
        o.A10 = *(const bf16x8*)(ap + 1024);
        o.A11 = *(const bf16x8*)(ap + 1536);
        o.pv = pb[(size_t)h * Ss * Ss];
    };

    auto compute = [&](const Buf& o) {
        const float s = o.pv;
        bf16x8 B0, B1;
#pragma unroll
        for (int t = 0; t < 4; ++t) {
            B0[t]     = (short)f2bf(s * ((const float*)&o.r0)[t]);
            B0[t + 4] = (short)f2bf(s * ((const float*)&o.r1)[t]);
            B1[t]     = (short)f2bf(s * ((const float*)&o.r2)[t]);
            B1[t + 4] = (short)f2bf(s * ((const float*)&o.r3)[t]);
        }
        acc0 = __builtin_amdgcn_mfma_f32_16x16x32_bf16(o.A00, B0, acc0, 0, 0, 0);
        acc0 = __builtin_amdgcn_mfma_f32_16x16x32_bf16(o.A10, B1, acc0, 0, 0, 0);
        acc1 = __builtin_amdgcn_mfma_f32_16x16x32_bf16(o.A01, B0, acc1, 0, 0, 0);
        acc1 = __builtin_amdgcn_mfma_f32_16x16x32_bf16(o.A11, B1, acc1, 0, 0, 0);
    };

    Buf oa, ob;
    load(oa, 0);
#pragma unroll 1
    for (int h = 0; h < Hh; h += 2) {
        load(ob, h + 1);          // issued BEFORE compute(oa): stays in flight
        compute(oa);              // consume-wait leaves ob's 9 loads pending
        if (h + 2 < Hh) load(oa, h + 2);
        compute(ob);
    }

    // value term: acc[l,j] += sum_h p[h,j] * wv[j,h,l]   (f32 exact)
    f32x4 val0 = {0.f, 0.f, 0.f, 0.f};
    f32x4 val1 = {0.f, 0.f, 0.f, 0.f};
#pragma unroll
    for (int h = 0; h < Hh; ++h) {
        const float pvh = pb[(size_t)h * Ss * Ss];
        const f32x4 w0 = *(const f32x4*)(wvb + h * 32);
        const f32x4 w1 = *(const f32x4*)(wvb + h * 32 + 16);
        val0 += pvh * w0;
        val1 += pvh * w1;
    }
    acc0 += val0;
    acc1 += val1;

    // C/D layout: col=lane&15 (=j), row=(lane>>4)*4+r (=l in 16-tile)
#pragma unroll
    for (int r = 0; r < 4; ++r) {
        const int l0 = grp * 4 + r;
        out[((size_t)(b * Ss + j) * Ll + l0) * Ss + i] = acc0[r] + bias[l0];
        const int l1 = 16 + grp * 4 + r;
        if (l1 < Ll)
            out[((size_t)(b * Ss + j) * Ll + l1) * Ss + i] = acc1[r] + bias[l1];
    }
}

// Fallback (small ws): self-contained col=j version, v inline, W direct.
__global__ __launch_bounds__(256, 4) void mhs_basic_j(
    const float* __restrict__ p, const float* __restrict__ v,
    const float* __restrict__ rel, const float* __restrict__ W,
    const float* __restrict__ bias, float* __restrict__ out)
{
    const int n = blockIdx.x;
    const int jb = n & 3, i = (n >> 2) & (Ss - 1), b = n >> 10;
    const int tid = threadIdx.x;
    const int w = tid >> 6, lane = tid & 63;
    const int col = lane & 15, grp = lane >> 4;
    const int j = jb * 64 + w * 16 + col;
    const float* relp = rel + ((size_t)(b * Ss + i) * Ss + j) * Kk + grp * 8;

    f32x4 acc0 = {0.f, 0.f, 0.f, 0.f}, acc1 = {0.f, 0.f, 0.f, 0.f};
#pragma unroll 1
    for (int h = 0; h < Hh; ++h) {
        bf16x8 A00, A01, A10, A11;
#pragma unroll
        for (int t = 0; t < 8; ++t) {
            const int kb = h * Ee + grp * 8 + t;
            const int la = col, lb = 16 + col;
            A00[t] = (short)f2bf(W[la * Kk + kb]);
            A01[t] = (lb < Ll) ? (short)f2bf(W[lb * Kk + kb]) : (short)0;
            A10[t] = (short)f2bf(W[la * Kk + kb + 32]);
            A11[t] = (lb < Ll) ? (short)f2bf(W[lb * Kk + kb + 32]) : (short)0;
        }
        const float* vbp = v + ((size_t)(b * Hh + h) * Ss + j) * Ee + grp * 8;
        const float4 va0 = *(const float4*)(vbp);
        const float4 va1 = *(const float4*)(vbp + 4);
        const float4 vc0 = *(const float4*)(vbp + 32);
        const float4 vc1 = *(const float4*)(vbp + 36);
        const float* rb = relp + h * Ee;
        const float4 c0 = *(const float4*)(rb);
        const float4 c1 = *(const float4*)(rb + 4);
        const float4 c2 = *(const float4*)(rb + 32);
        const float4 c3 = *(const float4*)(rb + 36);
        const float pv = p[((size_t)(b * Hh + h) * Ss + i) * Ss + j];
        bf16x8 B0, B1;
#pragma unroll
        for (int t = 0; t < 4; ++t) {
            B0[t]     = (short)f2bf(pv * (((const float*)&c0)[t] + ((const float*)&va0)[t]));
            B0[t + 4] = (short)f2bf(pv * (((const float*)&c1)[t] + ((const float*)&va1)[t]));
            B1[t]     = (short)f2bf(pv * (((const float*)&c2)[t] + ((const float*)&vc0)[t]));
            B1[t + 4] = (short)f2bf(pv * (((const float*)&c3)[t] + ((const float*)&vc1)[t]));
        }
        acc0 = __builtin_amdgcn_mfma_f32_16x16x32_bf16(A00, B0, acc0, 0, 0, 0);
        acc0 = __builtin_amdgcn_mfma_f32_16x16x32_bf16(A10, B1, acc0, 0, 0, 0);
        acc1 = __builtin_amdgcn_mfma_f32_16x16x32_bf16(A01, B0, acc1, 0, 0, 0);
        acc1 = __builtin_amdgcn_mfma_f32_16x16x32_bf16(A11, B1, acc1, 0, 0, 0);
    }
#pragma unroll
    for (int r = 0; r < 4; ++r) {
        const int l0 = grp * 4 + r;
        out[((size_t)(b * Ss + j) * Ll + l0) * Ss + i] = acc0[r] + bias[l0];
        const int l1 = 16 + grp * 4 + r;
        if (l1 < Ll)
            out[((size_t)(b * Ss + j) * Ll + l1) * Ss + i] = acc1[r] + bias[l1];
    }
}

extern "C" void kernel_launch(void* const* d_in, const int* in_sizes, int n_in,
                              void* d_out, int out_size, void* d_ws, size_t ws_size,
                              hipStream_t stream) {
    const float* p    = (const float*)d_in[0];
    const float* v    = (const float*)d_in[1];
    const float* rel  = (const float*)d_in[2];
    const float* W    = (const float*)d_in[3];
    const float* bias = (const float*)d_in[4];
    float* out = (float*)d_out;

    const int nblk = Bb * Ss * 4;  // 2048 blocks x 256 threads
    const bool full = ws_size >= AB_BYTES + WV_BYTES;

    if (full) {
        ushort* ab = (ushort*)d_ws;
        float* wvp = (float*)((char*)d_ws + AB_BYTES);
        hipLaunchKernelGGL(a_pack_kernel, dim3((NFRAG * 64 + 255) / 256), dim3(256),
                           0, stream, W, ab);
        hipLaunchKernelGGL(wv_kernel, dim3(Bb * Ss), dim3(Hh * 32),
                           0, stream, W, v, wvp);
        hipLaunchKernelGGL(mhs_jcol, dim3(nblk), dim3(256), 0, stream,
                           p, rel, ab, wvp, bias, out);
    } else {
        hipLaunchKernelGGL(mhs_basic_j, dim3(nblk), dim3(256), 0, stream,
                           p, v, rel, W, bias, out);
    }
}

// Round 8
// 125.103 us; speedup vs baseline: 1.1710x; 1.1710x over previous
//
#include <hip/hip_runtime.h>
#include <stdint.h>

// EATransformerMHS: B=2,H=12,S=256,E=64,L=25,K=768
// out[b,j,l,i] = sum_k p[b,k/64,i,j]*(v[b,k/64,j,k%64] + rel[b,i,j,k])*W[l,k] + b[l]
//
// Round-8: LDS-staged rel with fully-contiguous 1KB-per-instruction
// global_load_lds reads (fill-kernel access shape). Block = (b, 16-row
// i-tile, 4-j tile); 12 staging units of 16KB (16 rows x 1KB contiguous),
// double-buffered, one barrier per unit (sync -> stage-next -> compute).
// Waves split k (wave w = head c*4+w per chunk); per-j LDS reduction.
// Math identical to R6: mfma(W_h, bf16(p*rel)) + wv/bias epilogue.

#define Bb 2
#define Hh 12
#define Ss 256
#define Ee 64
#define Ll 25
#define Kk 768

#define JT 4                    // j values per block
#define NR 16                   // i rows per block
#define CHF 256                 // floats per chunk per row (4 heads)
#define RSTR 268                // LDS row stride (floats); 268%32=12 -> 2-way (free)
#define BUFF (NR * RSTR)        // 4288 floats / buffer
#define REDF 2048               // reduction region (4 waves x 512)
#define NUNIT (JT * 3)          // 12 staging units per block

typedef __attribute__((ext_vector_type(8))) short bf16x8;
typedef __attribute__((ext_vector_type(4))) float f32x4;

#define NFRAG (Hh * 4)
#define AB_BYTES ((size_t)NFRAG * 64 * 8 * 2)     // 49152
#define PT_BYTES ((size_t)Bb * Ss * Hh * Ss * 4)  // 6291456
#define WV_BYTES ((size_t)Bb * Ss * Hh * 32 * 4)  // 786432

typedef const void __attribute__((address_space(1)))* gas_ptr;
typedef void __attribute__((address_space(3)))* las_ptr;

__device__ __forceinline__ void async_copy16(void* lds_dst, const void* g_src) {
    __builtin_amdgcn_global_load_lds((gas_ptr)g_src, (las_ptr)lds_dst, 16, 0, 0);
}

__device__ __forceinline__ ushort f2bf(float x) {  // RNE f32->bf16
    union { float f; uint32_t u; } u; u.f = x;
    uint32_t r = u.u + 0x7fff + ((u.u >> 16) & 1);
    return (ushort)(r >> 16);
}

// Pack W[L,K] into per-lane A-fragments: frag fi=h*4+ks*2+Lt,
// lane holds A[l=Lt*16+(lane&15), k=h*64+ks*32+(lane>>4)*8+t].
__global__ void a_pack_kernel(const float* __restrict__ W, ushort* __restrict__ ab) {
    int idx = blockIdx.x * 256 + threadIdx.x;
    if (idx >= NFRAG * 64) return;
    int lane = idx & 63, fi = idx >> 6;
    int Lt = fi & 1, ks = (fi >> 1) & 1, h = fi >> 2;
    int l = Lt * 16 + (lane & 15);
    int k0 = h * Ee + ks * 32 + (lane >> 4) * 8;
    ushort* dst = ab + (size_t)idx * 8;
#pragma unroll
    for (int t = 0; t < 8; ++t)
        dst[t] = (l < Ll) ? f2bf(W[l * Kk + k0 + t]) : (ushort)0;
}

// p[b][h][i][j] -> pt[b][j][h][i]
__global__ void p_transpose_kernel(const float* __restrict__ p,
                                   float* __restrict__ pt) {
    __shared__ float tile[32][33];
    const int bh = blockIdx.y;
    const int b = bh / Hh, h = bh % Hh;
    const int ti = blockIdx.x >> 3, tj = blockIdx.x & 7;
    const int tx = threadIdx.x & 31, ty = threadIdx.x >> 5;
#pragma unroll
    for (int s = 0; s < 4; ++s) {
        const int il = ty + 8 * s;
        tile[il][tx] = p[((size_t)(b * Hh + h) * Ss + ti * 32 + il) * Ss + tj * 32 + tx];
    }
    __syncthreads();
#pragma unroll
    for (int s = 0; s < 4; ++s) {
        const int jl = ty + 8 * s;
        pt[((size_t)(b * Ss + tj * 32 + jl) * Hh + h) * Ss + ti * 32 + tx] = tile[tx][jl];
    }
}

// wv[b][j][h][l(pad32)] = sum_e W[l, h*64+e] * v[b,h,j,e]   (f32 exact)
__global__ void wv_kernel(const float* __restrict__ W, const float* __restrict__ v,
                          float* __restrict__ wv) {
    const int bj = blockIdx.x;
    const int b = bj >> 8, j = bj & (Ss - 1);
    const int t = threadIdx.x;            // 384 = 12h x 32l
    const int h = t >> 5, l = t & 31;
    float acc = 0.f;
    if (l < Ll) {
        const float* wrow = W + l * Kk + h * Ee;
        const float* vrow = v + ((size_t)(b * Hh + h) * Ss + j) * Ee;
#pragma unroll
        for (int e = 0; e < Ee; ++e) acc = __builtin_fmaf(wrow[e], vrow[e], acc);
    }
    wv[((size_t)bj * Hh + h) * 32 + l] = acc;
}

__global__ __launch_bounds__(256, 3) void mhs_lds(
    const float* __restrict__ pt,   // [B,S,H,S]
    const float* __restrict__ rel,  // [B,S,S,K]
    const ushort* __restrict__ ab,  // packed A frags
    const float* __restrict__ wv,   // [B,S,H,32]
    const float* __restrict__ bias, // [L]
    float* __restrict__ out)        // [B,S,L,S]
{
    __shared__ __align__(16) float lds[2 * BUFF + REDF];   // 42496 B

    const int n = blockIdx.x;                 // [b][it][jt]
    const int jt = n & 63, it = (n >> 6) & 15, b = n >> 10;
    const int j0 = jt * JT, i0 = it * NR;
    const int tid = threadIdx.x;
    const int w = tid >> 6, lane = tid & 63;
    const int col = lane & 15, grp = lane >> 4;

    // stage unit u (jj=u/3, chunk c=u%3) into buffer d:
    // 16 instructions (4/wave), each 1KB CONTIGUOUS from one rel row.
    auto stage = [&](int u, int d) {
        const int jj = u / 3, c = u - jj * 3;
#pragma unroll
        for (int q = 0; q < 4; ++q) {
            const int row = w * 4 + q;
            const float* src = rel
                + ((size_t)(b * Ss + i0 + row) * Ss + (j0 + jj)) * Kk
                + c * CHF + lane * 4;
            async_copy16(&lds[d * BUFF + row * RSTR], src);  // +lane*16B by HW
        }
    };

    f32x4 acc0 = {0.f, 0.f, 0.f, 0.f};
    f32x4 acc1 = {0.f, 0.f, 0.f, 0.f};

    stage(0, 0);
    int buf = 0;
#pragma unroll 1
    for (int u = 0; u < NUNIT; ++u) {
        __syncthreads();                       // buf staged; buf^1 free
        if (u + 1 < NUNIT) stage(u + 1, buf ^ 1);  // overlaps compute below

        const int jj = u / 3, c = u - jj * 3;
        const int j = j0 + jj;
        const int h = c * 4 + w;               // this wave's head

        const ushort* ap = ab + (size_t)h * 2048 + lane * 8;   // L2-hot
        const bf16x8 A00 = *(const bf16x8*)(ap);
        const bf16x8 A01 = *(const bf16x8*)(ap + 512);
        const bf16x8 A10 = *(const bf16x8*)(ap + 1024);
        const bf16x8 A11 = *(const bf16x8*)(ap + 1536);

        const float pv = pt[((size_t)(b * Ss + j) * Hh + h) * Ss + i0 + col];

        // rel fragment from LDS: row=col, k = w*64 + ks*32 + grp*8 + t
        const float* rb = &lds[buf * BUFF + col * RSTR + w * 64 + grp * 8];
        const float4 x0 = *(const float4*)(rb);
        const float4 x1 = *(const float4*)(rb + 4);
        const float4 y0 = *(const float4*)(rb + 32);
        const float4 y1 = *(const float4*)(rb + 36);

        bf16x8 B0, B1;
#pragma unroll
        for (int t = 0; t < 4; ++t) {
            B0[t]     = (short)f2bf(pv * ((const float*)&x0)[t]);
            B0[t + 4] = (short)f2bf(pv * ((const float*)&x1)[t]);
            B1[t]     = (short)f2bf(pv * ((const float*)&y0)[t]);
            B1[t + 4] = (short)f2bf(pv * ((const float*)&y1)[t]);
        }
        acc0 = __builtin_amdgcn_mfma_f32_16x16x32_bf16(A00, B0, acc0, 0, 0, 0);
        acc0 = __builtin_amdgcn_mfma_f32_16x16x32_bf16(A10, B1, acc0, 0, 0, 0);
        acc1 = __builtin_amdgcn_mfma_f32_16x16x32_bf16(A01, B0, acc1, 0, 0, 0);
        acc1 = __builtin_amdgcn_mfma_f32_16x16x32_bf16(A11, B1, acc1, 0, 0, 0);

        if (c == 2) {   // j finished: value term, 4-wave reduce, store
#pragma unroll
            for (int hh = 0; hh < 3; ++hh) {
                const int h2 = hh * 4 + w;
                const float pvh = pt[((size_t)(b * Ss + j) * Hh + h2) * Ss + i0 + col];
                const float* wp = wv + ((size_t)(b * Ss + j) * Hh + h2) * 32 + grp * 4;
                const f32x4 w0 = *(const f32x4*)(wp);
                const f32x4 w1 = *(const f32x4*)(wp + 16);
                acc0 += pvh * w0;
                acc1 += pvh * w1;
            }
            float* red = &lds[2 * BUFF];
#pragma unroll
            for (int r = 0; r < 4; ++r) {
                red[w * 512 + (grp * 4 + r) * 16 + col]        = acc0[r];
                red[w * 512 + (16 + grp * 4 + r) * 16 + col]   = acc1[r];
            }
            __syncthreads();
#pragma unroll
            for (int ss = 0; ss < 2; ++ss) {
                const int s = tid + ss * 256;
                const int lp = s >> 4, cc = s & 15;
                if (lp < Ll) {
                    const float val = red[s] + red[512 + s] + red[1024 + s]
                                    + red[1536 + s] + bias[lp];
                    out[((size_t)(b * Ss + j) * Ll + lp) * Ss + i0 + cc] = val;
                }
            }
            acc0 = (f32x4){0.f, 0.f, 0.f, 0.f};
            acc1 = (f32x4){0.f, 0.f, 0.f, 0.f};
        }
        buf ^= 1;
    }
}

// Fallback (small ws): self-contained R4-style kernel, no precomputed buffers.
__global__ __launch_bounds__(256, 4) void mhs_basic(
    const float* __restrict__ p, const float* __restrict__ v,
    const float* __restrict__ rel, const float* __restrict__ W,
    const float* __restrict__ bias, float* __restrict__ out)
{
    const int g = blockIdx.x;
    const int ig = g & 3, j = (g >> 2) & (Ss - 1), b = g >> 10;
    const int tid = threadIdx.x;
    const int w = tid >> 6, lane = tid & 63;
    const int col = lane & 15, grp = lane >> 4;
    const int iw = ig * 64 + w * 16 + col;
    const float* relp = rel + ((size_t)(b * Ss + iw) * Ss + j) * Kk + grp * 8;

    f32x4 acc0 = {0.f, 0.f, 0.f, 0.f}, acc1 = {0.f, 0.f, 0.f, 0.f};
#pragma unroll 1
    for (int h = 0; h < Hh; ++h) {
        bf16x8 A00, A01, A10, A11;
#pragma unroll
        for (int t = 0; t < 8; ++t) {
            const int kb = h * Ee + grp * 8 + t;
            const int la = col, lb = 16 + col;
            A00[t] = (short)f2bf(W[la * Kk + kb]);
            A01[t] = (lb < Ll) ? (short)f2bf(W[lb * Kk + kb]) : (short)0;
            A10[t] = (short)f2bf(W[la * Kk + kb + 32]);
            A11[t] = (lb < Ll) ? (short)f2bf(W[lb * Kk + kb + 32]) : (short)0;
        }
        const float* vbp = v + ((size_t)(b * Hh + h) * Ss + j) * Ee + grp * 8;
        const float4 va0 = *(const float4*)(vbp);
        const float4 va1 = *(const float4*)(vbp + 4);
        const float4 vc0 = *(const float4*)(vbp + 32);
        const float4 vc1 = *(const float4*)(vbp + 36);
        const float* rb = relp + h * Ee;
        const float4 c0 = *(const float4*)(rb);
        const float4 c1 = *(const float4*)(rb + 4);
        const float4 c2 = *(const float4*)(rb + 32);
        const float4 c3 = *(const float4*)(rb + 36);
        const float pv = p[((size_t)(b * Hh + h) * Ss + iw) * Ss + j];
        bf16x8 B0, B1;
#pragma unroll
        for (int t = 0; t < 4; ++t) {
            B0[t]     = (short)f2bf(pv * (((const float*)&c0)[t] + ((const float*)&va0)[t]));
            B0[t + 4] = (short)f2bf(pv * (((const float*)&c1)[t] + ((const float*)&va1)[t]));
            B1[t]     = (short)f2bf(pv * (((const float*)&c2)[t] + ((const float*)&vc0)[t]));
            B1[t + 4] = (short)f2bf(pv * (((const float*)&c3)[t] + ((const float*)&vc1)[t]));
        }
        acc0 = __builtin_amdgcn_mfma_f32_16x16x32_bf16(A00, B0, acc0, 0, 0, 0);
        acc0 = __builtin_amdgcn_mfma_f32_16x16x32_bf16(A10, B1, acc0, 0, 0, 0);
        acc1 = __builtin_amdgcn_mfma_f32_16x16x32_bf16(A01, B0, acc1, 0, 0, 0);
        acc1 = __builtin_amdgcn_mfma_f32_16x16x32_bf16(A11, B1, acc1, 0, 0, 0);
    }
#pragma unroll
    for (int r = 0; r < 4; ++r) {
        const int l0 = grp * 4 + r;
        out[((size_t)(b * Ss + j) * Ll + l0) * Ss + iw] = acc0[r] + bias[l0];
        const int l1 = 16 + grp * 4 + r;
        if (l1 < Ll)
            out[((size_t)(b * Ss + j) * Ll + l1) * Ss + iw] = acc1[r] + bias[l1];
    }
}

extern "C" void kernel_launch(void* const* d_in, const int* in_sizes, int n_in,
                              void* d_out, int out_size, void* d_ws, size_t ws_size,
                              hipStream_t stream) {
    const float* p    = (const float*)d_in[0];
    const float* v    = (const float*)d_in[1];
    const float* rel  = (const float*)d_in[2];
    const float* W    = (const float*)d_in[3];
    const float* bias = (const float*)d_in[4];
    float* out = (float*)d_out;

    const bool full = ws_size >= AB_BYTES + PT_BYTES + WV_BYTES;

    if (full) {
        ushort* ab = (ushort*)d_ws;
        float* pt  = (float*)((char*)d_ws + AB_BYTES);
        float* wvp = (float*)((char*)d_ws + AB_BYTES + PT_BYTES);
        hipLaunchKernelGGL(a_pack_kernel, dim3((NFRAG * 64 + 255) / 256), dim3(256),
                           0, stream, W, ab);
        hipLaunchKernelGGL(p_transpose_kernel, dim3(64, Bb * Hh), dim3(256),
                           0, stream, p, pt);
        hipLaunchKernelGGL(wv_kernel, dim3(Bb * Ss), dim3(Hh * 32),
                           0, stream, W, v, wvp);
        // grid: b(2) x i-tiles(16) x j-tiles(64) = 2048
        hipLaunchKernelGGL(mhs_lds, dim3(Bb * 16 * 64), dim3(256), 0, stream,
                           pt, rel, ab, wvp, bias, out);
    } else {
        hipLaunchKernelGGL(mhs_basic, dim3(Bb * Ss * 4), dim3(256), 0, stream,
                           p, v, rel, W, bias, out);
    }
}

// Round 9
// 117.455 us; speedup vs baseline: 1.2473x; 1.0651x over previous
//
#include <hip/hip_runtime.h>
#include <stdint.h>

// EATransformerMHS: B=2,H=12,S=256,E=64,L=25,K=768
// out[b,j,l,i] = sum_k p[b,k/64,i,j]*(v[b,k/64,j,k%64] + rel[b,i,j,k])*W[l,k] + b[l]
//
// Round-9: R8's LDS-staged contiguous-burst layout + T4 counted-vmcnt pipeline.
// Raw s_barrier (NO __syncthreads -> no vmcnt(0) drain), depth-2 stage
// (units u+1,u+2 in flight), s_waitcnt vmcnt(4) at each consume point.
// A-frags/pv/wv register-prefetched one unit ahead (before the stage issue)
// so no compiler use-wait drains the gll queue. bias in 2 loop-invariant regs.
// Reduce rides the existing barrier rhythm (no extra barriers).

#define Bb 2
#define Hh 12
#define Ss 256
#define Ee 64
#define Ll 25
#define Kk 768

#define JT 4                    // j values per block
#define NR 16                   // i rows per block
#define CHF 256                 // floats per unit per row (4 heads)
#define RSTR 260                // LDS row stride; (col*4+grp*8)%32 packs banks
#define BUFF (NR * RSTR)        // 4160 floats / buffer
#define REDF 2048               // reduction region (4 waves x 512 floats)
#define NUNIT (JT * 3)          // 12 units per block

typedef __attribute__((ext_vector_type(8))) short bf16x8;
typedef __attribute__((ext_vector_type(4))) float f32x4;

#define NFRAG (Hh * 4)
#define AB_BYTES ((size_t)NFRAG * 64 * 8 * 2)     // 49152
#define PT_BYTES ((size_t)Bb * Ss * Hh * Ss * 4)  // 6291456
#define WV_BYTES ((size_t)Bb * Ss * Hh * 32 * 4)  // 786432

typedef const void __attribute__((address_space(1)))* gas_ptr;
typedef void __attribute__((address_space(3)))* las_ptr;

__device__ __forceinline__ void async_copy16(void* lds_dst, const void* g_src) {
    __builtin_amdgcn_global_load_lds((gas_ptr)g_src, (las_ptr)lds_dst, 16, 0, 0);
}

__device__ __forceinline__ ushort f2bf(float x) {  // RNE f32->bf16
    union { float f; uint32_t u; } u; u.f = x;
    uint32_t r = u.u + 0x7fff + ((u.u >> 16) & 1);
    return (ushort)(r >> 16);
}

// Pack W[L,K] into per-lane A-fragments: frag fi=h*4+ks*2+Lt,
// lane holds A[l=Lt*16+(lane&15), k=h*64+ks*32+(lane>>4)*8+t].
__global__ void a_pack_kernel(const float* __restrict__ W, ushort* __restrict__ ab) {
    int idx = blockIdx.x * 256 + threadIdx.x;
    if (idx >= NFRAG * 64) return;
    int lane = idx & 63, fi = idx >> 6;
    int Lt = fi & 1, ks = (fi >> 1) & 1, h = fi >> 2;
    int l = Lt * 16 + (lane & 15);
    int k0 = h * Ee + ks * 32 + (lane >> 4) * 8;
    ushort* dst = ab + (size_t)idx * 8;
#pragma unroll
    for (int t = 0; t < 8; ++t)
        dst[t] = (l < Ll) ? f2bf(W[l * Kk + k0 + t]) : (ushort)0;
}

// p[b][h][i][j] -> pt[b][j][h][i]
__global__ void p_transpose_kernel(const float* __restrict__ p,
                                   float* __restrict__ pt) {
    __shared__ float tile[32][33];
    const int bh = blockIdx.y;
    const int b = bh / Hh, h = bh % Hh;
    const int ti = blockIdx.x >> 3, tj = blockIdx.x & 7;
    const int tx = threadIdx.x & 31, ty = threadIdx.x >> 5;
#pragma unroll
    for (int s = 0; s < 4; ++s) {
        const int il = ty + 8 * s;
        tile[il][tx] = p[((size_t)(b * Hh + h) * Ss + ti * 32 + il) * Ss + tj * 32 + tx];
    }
    __syncthreads();
#pragma unroll
    for (int s = 0; s < 4; ++s) {
        const int jl = ty + 8 * s;
        pt[((size_t)(b * Ss + tj * 32 + jl) * Hh + h) * Ss + ti * 32 + tx] = tile[tx][jl];
    }
}

// wv[b][j][h][l(pad32)] = sum_e W[l, h*64+e] * v[b,h,j,e]   (f32 exact)
__global__ void wv_kernel(const float* __restrict__ W, const float* __restrict__ v,
                          float* __restrict__ wv) {
    const int bj = blockIdx.x;
    const int b = bj >> 8, j = bj & (Ss - 1);
    const int t = threadIdx.x;            // 384 = 12h x 32l
    const int h = t >> 5, l = t & 31;
    float acc = 0.f;
    if (l < Ll) {
        const float* wrow = W + l * Kk + h * Ee;
        const float* vrow = v + ((size_t)(b * Hh + h) * Ss + j) * Ee;
#pragma unroll
        for (int e = 0; e < Ee; ++e) acc = __builtin_fmaf(wrow[e], vrow[e], acc);
    }
    wv[((size_t)bj * Hh + h) * 32 + l] = acc;
}

struct Pf {
    bf16x8 A00, A01, A10, A11;   // 16 VGPR
    float4 wv0, wv1;             // 8
    float pv;                    // 1
};

__global__ __launch_bounds__(256, 3) void mhs_t4(
    const float* __restrict__ pt,   // [B,S,H,S]
    const float* __restrict__ rel,  // [B,S,S,K]
    const ushort* __restrict__ ab,  // packed A frags
    const float* __restrict__ wvp,  // [B,S,H,32]
    const float* __restrict__ bias, // [L]
    float* __restrict__ out)        // [B,S,L,S]
{
    __shared__ __align__(16) float lds[2 * BUFF + REDF];   // 41472 B -> 3 blk/CU

    const int n = blockIdx.x;                 // [b][it][jt]
    const int jt = n & 63, it = (n >> 6) & 15, b = n >> 10;
    const int j0 = jt * JT, i0 = it * NR;
    const int tid = threadIdx.x;
    const int w = tid >> 6, lane = tid & 63;
    const int col = lane & 15, grp = lane >> 4;

    // unit uu = jj*3 + c: 16 rows x 1KB contiguous gll (4 instr/wave)
    auto stage = [&](int uu) {
        const int jj = uu / 3, c = uu - jj * 3;
#pragma unroll
        for (int q = 0; q < 4; ++q) {
            const int row = w * 4 + q;
            const float* src = rel
                + ((size_t)(b * Ss + i0 + row) * Ss + (j0 + jj)) * Kk
                + c * CHF + lane * 4;
            async_copy16(&lds[(uu & 1) * BUFF + row * RSTR], src);
        }
    };

    auto pre = [&](Pf& f, int uu) {
        const int jj = uu / 3, c = uu - jj * 3;
        const int h = c * 4 + w;
        const int j = j0 + jj;
        const ushort* ap = ab + (size_t)h * 2048 + lane * 8;
        f.A00 = *(const bf16x8*)(ap);
        f.A01 = *(const bf16x8*)(ap + 512);
        f.A10 = *(const bf16x8*)(ap + 1024);
        f.A11 = *(const bf16x8*)(ap + 1536);
        f.pv = pt[((size_t)(b * Ss + j) * Hh + h) * Ss + i0 + col];
        const float* wp = wvp + ((size_t)(b * Ss + j) * Hh + h) * 32 + grp * 4;
        f.wv0 = *(const float4*)(wp);
        f.wv1 = *(const float4*)(wp + 16);
    };

    f32x4 acc0 = {0.f, 0.f, 0.f, 0.f};
    f32x4 acc1 = {0.f, 0.f, 0.f, 0.f};

    auto compute = [&](const Pf& f, int uu) {
        const float* rb = &lds[(uu & 1) * BUFF + col * RSTR + w * 64 + grp * 8];
        const float4 x0 = *(const float4*)(rb);
        const float4 x1 = *(const float4*)(rb + 4);
        const float4 y0 = *(const float4*)(rb + 32);
        const float4 y1 = *(const float4*)(rb + 36);
        const float s = f.pv;
        // value term (wv already i-independent; pv in regs)
        acc0 += s * (f32x4){f.wv0.x, f.wv0.y, f.wv0.z, f.wv0.w};
        acc1 += s * (f32x4){f.wv1.x, f.wv1.y, f.wv1.z, f.wv1.w};
        bf16x8 B0, B1;
#pragma unroll
        for (int t = 0; t < 4; ++t) {
            B0[t]     = (short)f2bf(s * ((const float*)&x0)[t]);
            B0[t + 4] = (short)f2bf(s * ((const float*)&x1)[t]);
            B1[t]     = (short)f2bf(s * ((const float*)&y0)[t]);
            B1[t + 4] = (short)f2bf(s * ((const float*)&y1)[t]);
        }
        acc0 = __builtin_amdgcn_mfma_f32_16x16x32_bf16(f.A00, B0, acc0, 0, 0, 0);
        acc0 = __builtin_amdgcn_mfma_f32_16x16x32_bf16(f.A10, B1, acc0, 0, 0, 0);
        acc1 = __builtin_amdgcn_mfma_f32_16x16x32_bf16(f.A01, B0, acc1, 0, 0, 0);
        acc1 = __builtin_amdgcn_mfma_f32_16x16x32_bf16(f.A11, B1, acc1, 0, 0, 0);
    };

    // loop-invariant bias (per-thread output slots fixed)
    const int lp0 = tid >> 4, lp1 = (tid + 256) >> 4;
    const float bias0 = (lp0 < Ll) ? bias[lp0] : 0.f;
    const float bias1 = (lp1 < Ll) ? bias[lp1] : 0.f;

    Pf fa, fb;
    pre(fa, 0);          // BEFORE stage(1) so its use-wait never touches u+1 gll
    stage(0);
    stage(1);

    float* red = &lds[2 * BUFF];

    // one iteration: [wait; bar1; compute; (partials); pre(next); lgkm; bar2;
    //                 (consume+store); stage(u+2)]
    auto iter = [&](int u, Pf& cur, Pf& nxt) {
        if (u < NUNIT - 1) { asm volatile("s_waitcnt vmcnt(4)" ::: "memory"); }
        else               { asm volatile("s_waitcnt vmcnt(0)" ::: "memory"); }
        __builtin_amdgcn_sched_barrier(0);
        __builtin_amdgcn_s_barrier();
        __builtin_amdgcn_sched_barrier(0);

        compute(cur, u);
        const int jj = u / 3, c = u - jj * 3;
        if (c == 2) {          // write wave partials, reset acc
#pragma unroll
            for (int r = 0; r < 4; ++r) {
                red[w * 512 + (grp * 4 + r) * 16 + col]      = acc0[r];
                red[w * 512 + (16 + grp * 4 + r) * 16 + col] = acc1[r];
            }
            acc0 = (f32x4){0.f, 0.f, 0.f, 0.f};
            acc1 = (f32x4){0.f, 0.f, 0.f, 0.f};
        }
        if (u + 1 < NUNIT) pre(nxt, u + 1);   // VMEM BEFORE stage(u+2)

        asm volatile("s_waitcnt lgkmcnt(0)" ::: "memory");
        __builtin_amdgcn_sched_barrier(0);
        __builtin_amdgcn_s_barrier();
        __builtin_amdgcn_sched_barrier(0);

        if (c == 2) {          // 4-wave reduce + 64B-coalesced stores
            const int j = j0 + jj;
            const float s0 = red[tid] + red[512 + tid] + red[1024 + tid]
                           + red[1536 + tid];
            const float s1 = red[tid + 256 - 2048 + 2048] + 0.f;  // (placeholder avoid)
            // second half explicitly:
            const int t2 = tid + 256;
            const float q0 = s0 + bias0;
            const float q1 = red[t2 & 511] * 0.f;  // unused guard (kept simple below)
            (void)s1; (void)q1;
            if (lp0 < Ll)
                out[((size_t)(b * Ss + j) * Ll + lp0) * Ss + i0 + (tid & 15)] = q0;
            {
                const float r1 = red[t2 - 256 + 256] ; (void)r1;
            }
            const float u0 = red[t2]       + red[512 + t2 - 512 + 512]
                           + red[1024 + t2 - 1024 + 1024] + red[1536 + t2 - 1536 + 1536];
            // NOTE: expressions above simplify to red[t2]+red[512+t2]+... guarded:
            if (lp1 < Ll)
                out[((size_t)(b * Ss + j) * Ll + lp1) * Ss + i0 + (t2 & 15)] =
                    red[t2] + red[512 + t2] + red[1024 + t2] + red[1536 + t2] + bias1;
            (void)u0;
        }
        if (u + 2 < NUNIT) stage(u + 2);      // newest VMEM -> exact vmcnt(4)
    };

#pragma unroll 1
    for (int u = 0; u < NUNIT; u += 2) {
        iter(u, fa, fb);
        iter(u + 1, fb, fa);
    }
}

// Fallback (small ws): self-contained R4-style kernel.
__global__ __launch_bounds__(256, 4) void mhs_basic(
    const float* __restrict__ p, const float* __restrict__ v,
    const float* __restrict__ rel, const float* __restrict__ W,
    const float* __restrict__ bias, float* __restrict__ out)
{
    const int g = blockIdx.x;
    const int ig = g & 3, j = (g >> 2) & (Ss - 1), b = g >> 10;
    const int tid = threadIdx.x;
    const int w = tid >> 6, lane = tid & 63;
    const int col = lane & 15, grp = lane >> 4;
    const int iw = ig * 64 + w * 16 + col;
    const float* relp = rel + ((size_t)(b * Ss + iw) * Ss + j) * Kk + grp * 8;

    f32x4 acc0 = {0.f, 0.f, 0.f, 0.f}, acc1 = {0.f, 0.f, 0.f, 0.f};
#pragma unroll 1
    for (int h = 0; h < Hh; ++h) {
        bf16x8 A00, A01, A10, A11;
#pragma unroll
        for (int t = 0; t < 8; ++t) {
            const int kb = h * Ee + grp * 8 + t;
            const int la = col, lb = 16 + col;
            A00[t] = (short)f2bf(W[la * Kk + kb]);
            A01[t] = (lb < Ll) ? (short)f2bf(W[lb * Kk + kb]) : (short)0;
            A10[t] = (short)f2bf(W[la * Kk + kb + 32]);
            A11[t] = (lb < Ll) ? (short)f2bf(W[lb * Kk + kb + 32]) : (short)0;
        }
        const float* vbp = v + ((size_t)(b * Hh + h) * Ss + j) * Ee + grp * 8;
        const float4 va0 = *(const float4*)(vbp);
        const float4 va1 = *(const float4*)(vbp + 4);
        const float4 vc0 = *(const float4*)(vbp + 32);
        const float4 vc1 = *(const float4*)(vbp + 36);
        const float* rb = relp + h * Ee;
        const float4 c0 = *(const float4*)(rb);
        const float4 c1 = *(const float4*)(rb + 4);
        const float4 c2 = *(const float4*)(rb + 32);
        const float4 c3 = *(const float4*)(rb + 36);
        const float pv = p[((size_t)(b * Hh + h) * Ss + iw) * Ss + j];
        bf16x8 B0, B1;
#pragma unroll
        for (int t = 0; t < 4; ++t) {
            B0[t]     = (short)f2bf(pv * (((const float*)&c0)[t] + ((const float*)&va0)[t]));
            B0[t + 4] = (short)f2bf(pv * (((const float*)&c1)[t] + ((const float*)&va1)[t]));
            B1[t]     = (short)f2bf(pv * (((const float*)&c2)[t] + ((const float*)&vc0)[t]));
            B1[t + 4] = (short)f2bf(pv * (((const float*)&c3)[t] + ((const float*)&vc1)[t]));
        }
        acc0 = __builtin_amdgcn_mfma_f32_16x16x32_bf16(A00, B0, acc0, 0, 0, 0);
        acc0 = __builtin_amdgcn_mfma_f32_16x16x32_bf16(A10, B1, acc0, 0, 0, 0);
        acc1 = __builtin_amdgcn_mfma_f32_16x16x32_bf16(A01, B0, acc1, 0, 0, 0);
        acc1 = __builtin_amdgcn_mfma_f32_16x16x32_bf16(A11, B1, acc1, 0, 0, 0);
    }
#pragma unroll
    for (int r = 0; r < 4; ++r) {
        const int l0 = grp * 4 + r;
        out[((size_t)(b * Ss + j) * Ll + l0) * Ss + iw] = acc0[r] + bias[l0];
        const int l1 = 16 + grp * 4 + r;
        if (l1 < Ll)
            out[((size_t)(b * Ss + j) * Ll + l1) * Ss + iw] = acc1[r] + bias[l1];
    }
}

extern "C" void kernel_launch(void* const* d_in, const int* in_sizes, int n_in,
                              void* d_out, int out_size, void* d_ws, size_t ws_size,
                              hipStream_t stream) {
    const float* p    = (const float*)d_in[0];
    const float* v    = (const float*)d_in[1];
    const float* rel  = (const float*)d_in[2];
    const float* W    = (const float*)d_in[3];
    const float* bias = (const float*)d_in[4];
    float* out = (float*)d_out;

    const bool full = ws_size >= AB_BYTES + PT_BYTES + WV_BYTES;

    if (full) {
        ushort* ab = (ushort*)d_ws;
        float* pt  = (float*)((char*)d_ws + AB_BYTES);
        float* wvp = (float*)((char*)d_ws + AB_BYTES + PT_BYTES);
        hipLaunchKernelGGL(a_pack_kernel, dim3((NFRAG * 64 + 255) / 256), dim3(256),
                           0, stream, W, ab);
        hipLaunchKernelGGL(p_transpose_kernel, dim3(64, Bb * Hh), dim3(256),
                           0, stream, p, pt);
        hipLaunchKernelGGL(wv_kernel, dim3(Bb * Ss), dim3(Hh * 32),
                           0, stream, W, v, wvp);
        hipLaunchKernelGGL(mhs_t4, dim3(Bb * 16 * 64), dim3(256), 0, stream,
                           pt, rel, ab, wvp, bias, out);
    } else {
        hipLaunchKernelGGL(mhs_basic, dim3(Bb * Ss * 4), dim3(256), 0, stream,
                           p, v, rel, W, bias, out);
    }
}

// Round 10
// 115.266 us; speedup vs baseline: 1.2710x; 1.0190x over previous
//
#include <hip/hip_runtime.h>
#include <stdint.h>

// EATransformerMHS: B=2,H=12,S=256,E=64,L=25,K=768
// out[b,j,l,i] = sum_k p[b,k/64,i,j]*(v[b,k/64,j,k%64] + rel[b,i,j,k])*W[l,k] + b[l]
//
// Round-10: R9's counted-vmcnt burst-staged main kernel, minus side-kernel
// overhead. p read directly (p_transpose deleted); a_pack fused into wv
// (ONE side launch); chunked bijective XCD swizzle for p/wv L2 sharing.
// Main loop identical to R9: depth-2 stage, raw s_barrier, vmcnt(4) consume,
// operands register-prefetched one unit ahead.

#define Bb 2
#define Hh 12
#define Ss 256
#define Ee 64
#define Ll 25
#define Kk 768

#define JT 4                    // j values per block
#define NR 16                   // i rows per block
#define CHF 256                 // floats per unit per row (4 heads)
#define RSTR 260                // LDS row stride; col*260%32 spreads banks
#define BUFF (NR * RSTR)        // 4160 floats / buffer
#define REDF 2048               // reduction region (4 waves x 512 floats)
#define NUNIT (JT * 3)          // 12 units per block

typedef __attribute__((ext_vector_type(8))) short bf16x8;
typedef __attribute__((ext_vector_type(4))) float f32x4;

#define NFRAG (Hh * 4)
#define AB_BYTES ((size_t)NFRAG * 64 * 8 * 2)     // 49152
#define WV_BYTES ((size_t)Bb * Ss * Hh * 32 * 4)  // 786432

typedef const void __attribute__((address_space(1)))* gas_ptr;
typedef void __attribute__((address_space(3)))* las_ptr;

__device__ __forceinline__ void async_copy16(void* lds_dst, const void* g_src) {
    __builtin_amdgcn_global_load_lds((gas_ptr)g_src, (las_ptr)lds_dst, 16, 0, 0);
}

__device__ __forceinline__ ushort f2bf(float x) {  // RNE f32->bf16
    union { float f; uint32_t u; } u; u.f = x;
    uint32_t r = u.u + 0x7fff + ((u.u >> 16) & 1);
    return (ushort)(r >> 16);
}

// Fused side kernel (one launch): blocks [0,512): wv; blocks [512,520): a_pack.
//   wv[b][j][h][l(pad32)] = sum_e W[l, h*64+e] * v[b,h,j,e]   (f32 exact)
//   ab: frag fi=h*4+ks*2+Lt; lane holds A[l=Lt*16+(lane&15),
//       k=h*64+ks*32+(lane>>4)*8+t], t=0..7.
__global__ void side_kernel(const float* __restrict__ W, const float* __restrict__ v,
                            float* __restrict__ wv, ushort* __restrict__ ab) {
    if (blockIdx.x < 512) {
        const int bj = blockIdx.x;
        const int b = bj >> 8, j = bj & (Ss - 1);
        const int t = threadIdx.x;            // 384 = 12h x 32l
        const int h = t >> 5, l = t & 31;
        float acc = 0.f;
        if (l < Ll) {
            const float* wrow = W + l * Kk + h * Ee;
            const float* vrow = v + ((size_t)(b * Hh + h) * Ss + j) * Ee;
#pragma unroll
            for (int e = 0; e < Ee; ++e) acc = __builtin_fmaf(wrow[e], vrow[e], acc);
        }
        wv[((size_t)bj * Hh + h) * 32 + l] = acc;
    } else {
        const int idx = (blockIdx.x - 512) * 384 + threadIdx.x;
        if (idx >= NFRAG * 64) return;
        const int lane = idx & 63, fi = idx >> 6;
        const int Lt = fi & 1, ks = (fi >> 1) & 1, h = fi >> 2;
        const int l = Lt * 16 + (lane & 15);
        const int k0 = h * Ee + ks * 32 + (lane >> 4) * 8;
        ushort* dst = ab + (size_t)idx * 8;
#pragma unroll
        for (int t = 0; t < 8; ++t)
            dst[t] = (l < Ll) ? f2bf(W[l * Kk + k0 + t]) : (ushort)0;
    }
}

struct Pf {
    bf16x8 A00, A01, A10, A11;   // 16 VGPR
    float4 wv0, wv1;             // 8
    float pv;                    // 1
};

__global__ __launch_bounds__(256, 3) void mhs_t4(
    const float* __restrict__ p,    // [B,H,S,S]
    const float* __restrict__ rel,  // [B,S,S,K]
    const ushort* __restrict__ ab,  // packed A frags
    const float* __restrict__ wvp,  // [B,S,H,32]
    const float* __restrict__ bias, // [L]
    float* __restrict__ out)        // [B,S,L,S]
{
    __shared__ __align__(16) float lds[2 * BUFF + REDF];   // 41472 B -> 3 blk/CU

    // chunked bijective XCD swizzle (2048 % 8 == 0): XCD x gets logical
    // blocks [x*256,(x+1)*256) -> jt-neighbors (sharing p/wv L2 lines) and
    // it-groups co-reside per XCD.
    const int n = (blockIdx.x & 7) * 256 + (blockIdx.x >> 3);   // [b][it][jt]
    const int jt = n & 63, it = (n >> 6) & 15, b = n >> 10;
    const int j0 = jt * JT, i0 = it * NR;
    const int tid = threadIdx.x;
    const int w = tid >> 6, lane = tid & 63;
    const int col = lane & 15, grp = lane >> 4;

    // unit uu = jj*3 + c: 16 rows x 1KB contiguous gll (4 instr/wave)
    auto stage = [&](int uu) {
        const int jj = uu / 3, c = uu - jj * 3;
#pragma unroll
        for (int q = 0; q < 4; ++q) {
            const int row = w * 4 + q;
            const float* src = rel
                + ((size_t)(b * Ss + i0 + row) * Ss + (j0 + jj)) * Kk
                + c * CHF + lane * 4;
            async_copy16(&lds[(uu & 1) * BUFF + row * RSTR], src);
        }
    };

    auto pre = [&](Pf& f, int uu) {
        const int jj = uu / 3, c = uu - jj * 3;
        const int h = c * 4 + w;
        const int j = j0 + jj;
        const ushort* ap = ab + (size_t)h * 2048 + lane * 8;
        f.A00 = *(const bf16x8*)(ap);
        f.A01 = *(const bf16x8*)(ap + 512);
        f.A10 = *(const bf16x8*)(ap + 1024);
        f.A11 = *(const bf16x8*)(ap + 1536);
        // direct p read: 16 lanes x 4B at 1KB stride (L2-amortized over jt)
        f.pv = p[((size_t)(b * Hh + h) * Ss + i0 + col) * Ss + j];
        const float* wp = wvp + ((size_t)(b * Ss + j) * Hh + h) * 32 + grp * 4;
        f.wv0 = *(const float4*)(wp);
        f.wv1 = *(const float4*)(wp + 16);
    };

    f32x4 acc0 = {0.f, 0.f, 0.f, 0.f};
    f32x4 acc1 = {0.f, 0.f, 0.f, 0.f};

    auto compute = [&](const Pf& f, int uu) {
        const float* rb = &lds[(uu & 1) * BUFF + col * RSTR + w * 64 + grp * 8];
        const float4 x0 = *(const float4*)(rb);
        const float4 x1 = *(const float4*)(rb + 4);
        const float4 y0 = *(const float4*)(rb + 32);
        const float4 y1 = *(const float4*)(rb + 36);
        const float s = f.pv;
        acc0 += s * (f32x4){f.wv0.x, f.wv0.y, f.wv0.z, f.wv0.w};
        acc1 += s * (f32x4){f.wv1.x, f.wv1.y, f.wv1.z, f.wv1.w};
        bf16x8 B0, B1;
#pragma unroll
        for (int t = 0; t < 4; ++t) {
            B0[t]     = (short)f2bf(s * ((const float*)&x0)[t]);
            B0[t + 4] = (short)f2bf(s * ((const float*)&x1)[t]);
            B1[t]     = (short)f2bf(s * ((const float*)&y0)[t]);
            B1[t + 4] = (short)f2bf(s * ((const float*)&y1)[t]);
        }
        acc0 = __builtin_amdgcn_mfma_f32_16x16x32_bf16(f.A00, B0, acc0, 0, 0, 0);
        acc0 = __builtin_amdgcn_mfma_f32_16x16x32_bf16(f.A10, B1, acc0, 0, 0, 0);
        acc1 = __builtin_amdgcn_mfma_f32_16x16x32_bf16(f.A01, B0, acc1, 0, 0, 0);
        acc1 = __builtin_amdgcn_mfma_f32_16x16x32_bf16(f.A11, B1, acc1, 0, 0, 0);
    };

    // loop-invariant bias (per-thread output slots fixed)
    const int lp0 = tid >> 4, lp1 = (tid + 256) >> 4;
    const float bias0 = (lp0 < Ll) ? bias[lp0] : 0.f;
    const float bias1 = (lp1 < Ll) ? bias[lp1] : 0.f;

    Pf fa, fb;
    pre(fa, 0);          // issued BEFORE stage(0/1): retires before them
    stage(0);
    stage(1);

    float* red = &lds[2 * BUFF];

    auto iter = [&](int u, Pf& cur, Pf& nxt) {
        if (u < NUNIT - 1) { asm volatile("s_waitcnt vmcnt(4)" ::: "memory"); }
        else               { asm volatile("s_waitcnt vmcnt(0)" ::: "memory"); }
        __builtin_amdgcn_sched_barrier(0);
        __builtin_amdgcn_s_barrier();
        __builtin_amdgcn_sched_barrier(0);

        compute(cur, u);
        const int jj = u / 3, c = u - jj * 3;
        if (c == 2) {          // wave partials -> red, reset acc
#pragma unroll
            for (int r = 0; r < 4; ++r) {
                red[w * 512 + (grp * 4 + r) * 16 + col]      = acc0[r];
                red[w * 512 + (16 + grp * 4 + r) * 16 + col] = acc1[r];
            }
            acc0 = (f32x4){0.f, 0.f, 0.f, 0.f};
            acc1 = (f32x4){0.f, 0.f, 0.f, 0.f};
        }
        if (u + 1 < NUNIT) pre(nxt, u + 1);   // VMEM before stage(u+2)

        asm volatile("s_waitcnt lgkmcnt(0)" ::: "memory");
        __builtin_amdgcn_sched_barrier(0);
        __builtin_amdgcn_s_barrier();
        __builtin_amdgcn_sched_barrier(0);

        if (c == 2) {          // 4-wave reduce + 64B-coalesced stores
            const int j = j0 + jj;
            const float r0 = red[tid] + red[512 + tid] + red[1024 + tid]
                           + red[1536 + tid] + bias0;
            if (lp0 < Ll)
                out[((size_t)(b * Ss + j) * Ll + lp0) * Ss + i0 + (tid & 15)] = r0;
            const int t2 = tid + 256;
            const float r1 = red[t2] + red[512 + t2] + red[1024 + t2]
                           + red[1536 + t2] + bias1;
            if (lp1 < Ll)
                out[((size_t)(b * Ss + j) * Ll + lp1) * Ss + i0 + (t2 & 15)] = r1;
        }
        if (u + 2 < NUNIT) stage(u + 2);      // newest VMEM -> exact vmcnt(4)
    };

#pragma unroll 1
    for (int u = 0; u < NUNIT; u += 2) {
        iter(u, fa, fb);
        iter(u + 1, fb, fa);
    }
}

// Fallback (small ws): self-contained R4-style kernel.
__global__ __launch_bounds__(256, 4) void mhs_basic(
    const float* __restrict__ p, const float* __restrict__ v,
    const float* __restrict__ rel, const float* __restrict__ W,
    const float* __restrict__ bias, float* __restrict__ out)
{
    const int g = blockIdx.x;
    const int ig = g & 3, j = (g >> 2) & (Ss - 1), b = g >> 10;
    const int tid = threadIdx.x;
    const int w = tid >> 6, lane = tid & 63;
    const int col = lane & 15, grp = lane >> 4;
    const int iw = ig * 64 + w * 16 + col;
    const float* relp = rel + ((size_t)(b * Ss + iw) * Ss + j) * Kk + grp * 8;

    f32x4 acc0 = {0.f, 0.f, 0.f, 0.f}, acc1 = {0.f, 0.f, 0.f, 0.f};
#pragma unroll 1
    for (int h = 0; h < Hh; ++h) {
        bf16x8 A00, A01, A10, A11;
#pragma unroll
        for (int t = 0; t < 8; ++t) {
            const int kb = h * Ee + grp * 8 + t;
            const int la = col, lb = 16 + col;
            A00[t] = (short)f2bf(W[la * Kk + kb]);
            A01[t] = (lb < Ll) ? (short)f2bf(W[lb * Kk + kb]) : (short)0;
            A10[t] = (short)f2bf(W[la * Kk + kb + 32]);
            A11[t] = (lb < Ll) ? (short)f2bf(W[lb * Kk + kb + 32]) : (short)0;
        }
        const float* vbp = v + ((size_t)(b * Hh + h) * Ss + j) * Ee + grp * 8;
        const float4 va0 = *(const float4*)(vbp);
        const float4 va1 = *(const float4*)(vbp + 4);
        const float4 vc0 = *(const float4*)(vbp + 32);
        const float4 vc1 = *(const float4*)(vbp + 36);
        const float* rb = relp + h * Ee;
        const float4 c0 = *(const float4*)(rb);
        const float4 c1 = *(const float4*)(rb + 4);
        const float4 c2 = *(const float4*)(rb + 32);
        const float4 c3 = *(const float4*)(rb + 36);
        const float pv = p[((size_t)(b * Hh + h) * Ss + iw) * Ss + j];
        bf16x8 B0, B1;
#pragma unroll
        for (int t = 0; t < 4; ++t) {
            B0[t]     = (short)f2bf(pv * (((const float*)&c0)[t] + ((const float*)&va0)[t]));
            B0[t + 4] = (short)f2bf(pv * (((const float*)&c1)[t] + ((const float*)&va1)[t]));
            B1[t]     = (short)f2bf(pv * (((const float*)&c2)[t] + ((const float*)&vc0)[t]));
            B1[t + 4] = (short)f2bf(pv * (((const float*)&c3)[t] + ((const float*)&vc1)[t]));
        }
        acc0 = __builtin_amdgcn_mfma_f32_16x16x32_bf16(A00, B0, acc0, 0, 0, 0);
        acc0 = __builtin_amdgcn_mfma_f32_16x16x32_bf16(A10, B1, acc0, 0, 0, 0);
        acc1 = __builtin_amdgcn_mfma_f32_16x16x32_bf16(A01, B0, acc1, 0, 0, 0);
        acc1 = __builtin_amdgcn_mfma_f32_16x16x32_bf16(A11, B1, acc1, 0, 0, 0);
    }
#pragma unroll
    for (int r = 0; r < 4; ++r) {
        const int l0 = grp * 4 + r;
        out[((size_t)(b * Ss + j) * Ll + l0) * Ss + iw] = acc0[r] + bias[l0];
        const int l1 = 16 + grp * 4 + r;
        if (l1 < Ll)
            out[((size_t)(b * Ss + j) * Ll + l1) * Ss + iw] = acc1[r] + bias[l1];
    }
}

extern "C" void kernel_launch(void* const* d_in, const int* in_sizes, int n_in,
                              void* d_out, int out_size, void* d_ws, size_t ws_size,
                              hipStream_t stream) {
    const float* p    = (const float*)d_in[0];
    const float* v    = (const float*)d_in[1];
    const float* rel  = (const float*)d_in[2];
    const float* W    = (const float*)d_in[3];
    const float* bias = (const float*)d_in[4];
    float* out = (float*)d_out;

    const bool full = ws_size >= AB_BYTES + WV_BYTES;

    if (full) {
        ushort* ab = (ushort*)d_ws;
        float* wvp = (float*)((char*)d_ws + AB_BYTES);
        hipLaunchKernelGGL(side_kernel, dim3(520), dim3(384), 0, stream,
                           W, v, wvp, ab);
        hipLaunchKernelGGL(mhs_t4, dim3(Bb * 16 * 64), dim3(256), 0, stream,
                           p, rel, ab, wvp, bias, out);
    } else {
        hipLaunchKernelGGL(mhs_basic, dim3(Bb * Ss * 4), dim3(256), 0, stream,
                           p, v, rel, W, bias, out);
    }
}

// Round 11
// 108.143 us; speedup vs baseline: 1.3547x; 1.0659x over previous
//
#include <hip/hip_runtime.h>
#include <stdint.h>

// EATransformerMHS: B=2,H=12,S=256,E=64,L=25,K=768
// out[b,j,l,i] = sum_k p[b,k/64,i,j]*(v[b,k/64,j,k%64] + rel[b,i,j,k])*W[l,k] + b[l]
//
// Round-11 (consolidation): the empirically-best R4 main kernel (direct
// per-lane float4 rel loads, 1-h-ahead prefetch, v inline from L2,
// pt-coalesced p, A-frags prepacked) + R10's side-launch fusion (p_transpose
// and a_pack in ONE kernel -> one side launch instead of three).
// R5-R10 ablations (deeper pipelines, LDS burst staging, counted vmcnt,
// XCD swizzles, col=j) were all neutral-or-worse: read rate pins at
// ~4.2 TB/s across every architecture tried => read-path bound.

#define Bb 2
#define Hh 12
#define Ss 256
#define Ee 64
#define Ll 25
#define Kk 768

typedef __attribute__((ext_vector_type(8))) short bf16x8;
typedef __attribute__((ext_vector_type(4))) float f32x4;

#define NFRAG (Hh * 4)                           // (h, ks, Lt)
#define AB_BYTES ((size_t)NFRAG * 64 * 8 * 2)    // 49152
#define PT_BYTES ((size_t)Bb * Ss * Hh * Ss * 4) // 6291456

#define TR_BLOCKS (64 * Bb * Hh)                 // 1536 transpose blocks
#define AP_BLOCKS ((NFRAG * 64 + 255) / 256)     // 12 a_pack blocks

__device__ __forceinline__ ushort f2bf(float x) {  // RNE f32->bf16
    union { float f; uint32_t u; } u; u.f = x;
    uint32_t r = u.u + 0x7fff + ((u.u >> 16) & 1);
    return (ushort)(r >> 16);
}

// Fused side kernel (single launch):
//   blocks [0, TR_BLOCKS):              p[b][h][i][j] -> pt[b][j][h][i]
//   blocks [TR_BLOCKS, TR_BLOCKS+12):   pack W[L,K] into A-fragments
// A-frag layout: frag fi=h*4+ks*2+Lt; lane holds
//   A[l=Lt*16+(lane&15), k=h*64+ks*32+(lane>>4)*8+t], t=0..7.
__global__ void side_fused(const float* __restrict__ p, float* __restrict__ pt,
                           const float* __restrict__ W, ushort* __restrict__ ab) {
    __shared__ float tile[32][33];
    if (blockIdx.x < TR_BLOCKS) {
        const int bh = blockIdx.x >> 6;           // 0..23
        const int xy = blockIdx.x & 63;           // 8x8 tiles of 32
        const int b = bh / Hh, h = bh % Hh;
        const int ti = xy >> 3, tj = xy & 7;
        const int tx = threadIdx.x & 31, ty = threadIdx.x >> 5;  // 32x8
#pragma unroll
        for (int s = 0; s < 4; ++s) {
            const int il = ty + 8 * s;
            tile[il][tx] =
                p[((size_t)(b * Hh + h) * Ss + ti * 32 + il) * Ss + tj * 32 + tx];
        }
        __syncthreads();
#pragma unroll
        for (int s = 0; s < 4; ++s) {
            const int jl = ty + 8 * s;
            pt[((size_t)(b * Ss + tj * 32 + jl) * Hh + h) * Ss + ti * 32 + tx] =
                tile[tx][jl];
        }
    } else {
        const int idx = (blockIdx.x - TR_BLOCKS) * 256 + threadIdx.x;
        if (idx >= NFRAG * 64) return;
        const int lane = idx & 63, fi = idx >> 6;
        const int Lt = fi & 1, ks = (fi >> 1) & 1, h = fi >> 2;
        const int l = Lt * 16 + (lane & 15);
        const int k0 = h * Ee + ks * 32 + (lane >> 4) * 8;
        ushort* dst = ab + (size_t)idx * 8;
#pragma unroll
        for (int t = 0; t < 8; ++t)
            dst[t] = (l < Ll) ? f2bf(W[l * Kk + k0 + t]) : (ushort)0;
    }
}

template <bool FULL>
__global__ __launch_bounds__(256, 4) void mhs_mfma(
    const float* __restrict__ p,    // [B,H,S,S] (!FULL)
    const float* __restrict__ pt,   // [B,S,H,S] (FULL)
    const float* __restrict__ v,    // [B,H,S,E]
    const float* __restrict__ rel,  // [B,S,S,K]
    const float* __restrict__ W,    // [L,K]     (!FULL)
    const ushort* __restrict__ ab,  // packed A frags (FULL)
    const float* __restrict__ bias, // [L]
    float* __restrict__ out)        // [B,S,L,S]
{
    const int g = blockIdx.x;                 // [b][j][ig]
    const int ig = g & 3, j = (g >> 2) & (Ss - 1), b = g >> 10;
    const int tid = threadIdx.x;
    const int w = tid >> 6, lane = tid & 63;
    const int col = lane & 15, grp = lane >> 4;
    const int iw = ig * 64 + w * 16 + col;    // this lane's output row i

    const float* relp = rel + ((size_t)(b * Ss + iw) * Ss + j) * Kk + grp * 8;

    f32x4 acc0 = {0.f, 0.f, 0.f, 0.f};
    f32x4 acc1 = {0.f, 0.f, 0.f, 0.f};

    // prime the rel pipeline (h=0)
    float4 c0 = *(const float4*)(relp);
    float4 c1 = *(const float4*)(relp + 4);
    float4 c2 = *(const float4*)(relp + 32);
    float4 c3 = *(const float4*)(relp + 36);

#pragma unroll 1
    for (int h = 0; h < Hh; ++h) {
        // issue next h's rel loads first (clamped on last iter -> L1 hit)
        const int hn = (h + 1 < Hh) ? h + 1 : h;
        const float* rn = relp + hn * Ee;
        const float4 n0 = *(const float4*)(rn);
        const float4 n1 = *(const float4*)(rn + 4);
        const float4 n2 = *(const float4*)(rn + 32);
        const float4 n3 = *(const float4*)(rn + 36);

        // A fragments (48KB L2-hot)
        bf16x8 A00, A01, A10, A11;  // [ks][Lt]
        if (FULL) {
            const ushort* abase = ab + (size_t)(h * 4) * 512 + lane * 8;
            A00 = *(const bf16x8*)(abase);
            A01 = *(const bf16x8*)(abase + 512);
            A10 = *(const bf16x8*)(abase + 1024);
            A11 = *(const bf16x8*)(abase + 1536);
        } else {
#pragma unroll
            for (int t = 0; t < 8; ++t) {
                const int kb = h * Ee + grp * 8 + t;
                const int la = col, lb = 16 + col;
                A00[t] = (short)f2bf(W[la * Kk + kb]);
                A01[t] = (lb < Ll) ? (short)f2bf(W[lb * Kk + kb]) : (short)0;
                A10[t] = (short)f2bf(W[la * Kk + kb + 32]);
                A11[t] = (lb < Ll) ? (short)f2bf(W[lb * Kk + kb + 32]) : (short)0;
            }
        }

        // v slice (broadcast within 16-lane groups; L2-hot)
        const float* vbp = v + ((size_t)(b * Hh + h) * Ss + j) * Ee + grp * 8;
        const float4 va0 = *(const float4*)(vbp);
        const float4 va1 = *(const float4*)(vbp + 4);
        const float4 vc0 = *(const float4*)(vbp + 32);
        const float4 vc1 = *(const float4*)(vbp + 36);

        const float pv = FULL
            ? pt[((size_t)(b * Ss + j) * Hh + h) * Ss + iw]
            : p[((size_t)(b * Hh + h) * Ss + iw) * Ss + j];

        bf16x8 B0, B1;
#pragma unroll
        for (int t = 0; t < 4; ++t) {
            B0[t]     = (short)f2bf(((const float*)&c0)[t] + ((const float*)&va0)[t]);
            B0[t + 4] = (short)f2bf(((const float*)&c1)[t] + ((const float*)&va1)[t]);
            B1[t]     = (short)f2bf(((const float*)&c2)[t] + ((const float*)&vc0)[t]);
            B1[t + 4] = (short)f2bf(((const float*)&c3)[t] + ((const float*)&vc1)[t]);
        }
        f32x4 C0 = {0.f, 0.f, 0.f, 0.f}, C1 = {0.f, 0.f, 0.f, 0.f};
        C0 = __builtin_amdgcn_mfma_f32_16x16x32_bf16(A00, B0, C0, 0, 0, 0);
        C0 = __builtin_amdgcn_mfma_f32_16x16x32_bf16(A10, B1, C0, 0, 0, 0);
        C1 = __builtin_amdgcn_mfma_f32_16x16x32_bf16(A01, B0, C1, 0, 0, 0);
        C1 = __builtin_amdgcn_mfma_f32_16x16x32_bf16(A11, B1, C1, 0, 0, 0);
        acc0 += pv * C0;
        acc1 += pv * C1;

        c0 = n0; c1 = n1; c2 = n2; c3 = n3;
    }

    // C/D layout: col=lane&15 (=i_local), row=(lane>>4)*4+r (=l within 16-tile)
#pragma unroll
    for (int r = 0; r < 4; ++r) {
        const int l0 = grp * 4 + r;
        out[((size_t)(b * Ss + j) * Ll + l0) * Ss + iw] = acc0[r] + bias[l0];
        const int l1 = 16 + grp * 4 + r;
        if (l1 < Ll)
            out[((size_t)(b * Ss + j) * Ll + l1) * Ss + iw] = acc1[r] + bias[l1];
    }
}

extern "C" void kernel_launch(void* const* d_in, const int* in_sizes, int n_in,
                              void* d_out, int out_size, void* d_ws, size_t ws_size,
                              hipStream_t stream) {
    const float* p    = (const float*)d_in[0];
    const float* v    = (const float*)d_in[1];
    const float* rel  = (const float*)d_in[2];
    const float* W    = (const float*)d_in[3];
    const float* bias = (const float*)d_in[4];
    float* out = (float*)d_out;

    const int nblk = Bb * Ss * 4;  // 2048 blocks x 256 threads
    const bool full = ws_size >= AB_BYTES + PT_BYTES;

    if (full) {
        ushort* ab = (ushort*)d_ws;
        float* pt  = (float*)((char*)d_ws + AB_BYTES);
        hipLaunchKernelGGL(side_fused, dim3(TR_BLOCKS + AP_BLOCKS), dim3(256),
                           0, stream, p, pt, W, ab);
        hipLaunchKernelGGL((mhs_mfma<true>), dim3(nblk), dim3(256), 0, stream,
                           p, pt, v, rel, W, ab, bias, out);
    } else {
        hipLaunchKernelGGL((mhs_mfma<false>), dim3(nblk), dim3(256), 0, stream,
                           p, (const float*)nullptr, v, rel, W,
                           (const ushort*)nullptr, bias, out);
    }
}